// Round 17
// baseline (285.526 us; speedup 1.0000x reference)
//
#include <hip/hip_runtime.h>

// ---------------------------------------------------------------------------
// Fused MHA: B=2, T=2048, M=2048, H=16, D=128, causal, qk-centered-RMS-norm,
// half-split rotary, QK_SCALE = 1/D.
// Pipeline: prep (cast|transpose+PAIR-PERMUTE q/k|rope fused) -> QKV GEMM v5
// (128x256 tile, 4 waves of 64(?)... per-wave 128x64, ratio 2.67, 2 blk/CU,
// fused norm+rope epilogue) -> flash attn v3 -> out GEMM v5 (fp32 out).
// Pair permutation: head position p holds d(p) = (p>>1) + (p&1)*64 -> rope
// partner is adjacent lane (shfl_xor 1); QK^T invariant.
// ---------------------------------------------------------------------------

#define NB 2
#define NT 2048
#define NM 2048
#define NH 16
#define ND 128

typedef __attribute__((ext_vector_type(4))) float f32x4;
typedef __attribute__((ext_vector_type(8))) short bf16x8;
typedef __attribute__((ext_vector_type(4))) short bf16x4;

#define AS1 __attribute__((address_space(1)))
#define AS3 __attribute__((address_space(3)))

#define SW(r) (((r) ^ ((r) >> 2)) & 3)

__device__ __forceinline__ unsigned short f2bf(float f){
  unsigned int u = __float_as_uint(f);
  u = (u + 0x7fffu + ((u >> 16) & 1u)) >> 16;   // RNE
  return (unsigned short)u;
}
__device__ __forceinline__ float bf2f(short s){
  return __uint_as_float(((unsigned int)(unsigned short)s) << 16);
}
__device__ __forceinline__ void gload_lds16(const void* g, void* l){
  __builtin_amdgcn_global_load_lds((const AS1 void*)g, (AS3 void*)l, 16, 0, 0);
}

// ------------- fused prep: cast x | transpose weights | rope table ---------
// q/k weight rows stored PAIR-PERMUTED in-head: n' = h*128 + 2*(d&63)+(d>>6)
__global__ __launch_bounds__(256) void prep_k(const float* __restrict__ x,
                                              const float* __restrict__ wq,
                                              const float* __restrict__ wk,
                                              const float* __restrict__ wv,
                                              const float* __restrict__ wo,
                                              short* __restrict__ xb,
                                              short* __restrict__ wT,
                                              float* __restrict__ ctab,
                                              float* __restrict__ stab){
  __shared__ float tl[32][33];
  const int bid = blockIdx.x, tid = threadIdx.x;
  if (bid < 8192){
    size_t gid = (size_t)bid * 256 + tid;
    float4 v = *(const float4*)(x + gid * 4);
    bf16x4 o;
    o[0] = (short)f2bf(v.x); o[1] = (short)f2bf(v.y);
    o[2] = (short)f2bf(v.z); o[3] = (short)f2bf(v.w);
    *(bf16x4*)(xb + gid * 4) = o;
  } else if (bid < 24576){
    int tb = bid - 8192;
    int z = tb >> 12, rem = tb & 4095;
    int n0 = (rem & 63) * 32, k0 = (rem >> 6) * 32;
    const float* src = (z == 0) ? wq : (z == 1) ? wk : (z == 2) ? wv : wo;
    short* dst = wT + (size_t)z * 2048 * 2048;
    int cx = tid & 31, ry = tid >> 5; // 0..7
    #pragma unroll
    for (int p = 0; p < 4; ++p)
      tl[ry + 8 * p][cx] = src[(size_t)(k0 + ry + 8 * p) * 2048 + n0 + cx];
    __syncthreads();
    #pragma unroll
    for (int p = 0; p < 4; ++p){
      int n = n0 + ry + 8 * p;
      if (z < 2){
        int d = n & 127;
        n = (n & ~127) | (((d & 63) << 1) | (d >> 6));
      }
      dst[(size_t)n * 2048 + k0 + cx] = (short)f2bf(tl[cx][ry + 8 * p]);
    }
  } else {
    int t = (bid - 24576) * 4 + (tid >> 6);
    int i = tid & 63;
    float freq = __expf(-(float)i * (9.210340371976184f / 64.0f)); // ln(10000)
    float ang = (float)t * freq;
    ctab[t * 64 + i] = cosf(ang);
    stab[t * 64 + i] = sinf(ang);
  }
}

// ---------------------------------------------------------------------------
// QKV GEMM v5: 128x256 tile, BK=32, 4 waves (1M x 4N; per-wave 128x64),
// 256 threads, 48 KiB LDS, 2 blocks/CU. 12 ds_read / 32 MFMA per kt per wave
// (ratio 2.67 -> MFMA-bound). Fused norm+rope epilogue (pair-permuted).
// N-tile spans 2 heads. V written tile-transposed.
// ---------------------------------------------------------------------------
#define NKT2 64   // 2048 / 32
__global__ __launch_bounds__(256, 2) void gemm256_k(const short* __restrict__ A,
                                                    const short* __restrict__ Bt,
                                                    short* __restrict__ Cv,
                                                    short* __restrict__ Cn,
                                                    const float* __restrict__ gq,
                                                    const float* __restrict__ bq,
                                                    const float* __restrict__ gk,
                                                    const float* __restrict__ bk,
                                                    const float* __restrict__ ctab,
                                                    const float* __restrict__ stab){
  extern __shared__ char lds[];   // A[2][8KB] @0 | B[2][16KB] @16384
  const int tid = threadIdx.x;
  const int wid = tid >> 6, lane = tid & 63;   // wid 0..3
  const int lrow = lane & 15, g8 = lane >> 4;
  const int Kdim = 2048;

  // XCD-aware bijective swizzle over 768 blocks (768 % 8 == 0)
  int bid = blockIdx.x;
  int s = (bid & 7) * 96 + (bid >> 3);
  const int bx = s & 31;        // 32 m-tiles (128 rows)
  const int by = s >> 5;        // 24 n-tiles (256 cols)
  const int m0 = bx * 128, n0 = by * 256;

  const int ar = lane >> 2;                       // row within 16-row chunk
  const int ag = (lane & 3) ^ SW(ar);             // inverse-swizzled granule
  const short* Ab = A  + (size_t)(m0 + wid * 32 + ar) * Kdim + ag * 8;
  const short* Bb = Bt + (size_t)(n0 + wid * 64 + ar) * Kdim + ag * 8;

  f32x4 acc[8][4] = {};

  auto STAGE = [&](int c, int kt){
    #pragma unroll
    for (int i = 0; i < 2; ++i)
      gload_lds16(Ab + (size_t)(i * 16) * Kdim + kt * 32,
                  lds + c * 8192 + wid * 2048 + i * 1024);
    #pragma unroll
    for (int j = 0; j < 4; ++j)
      gload_lds16(Bb + (size_t)(j * 16) * Kdim + kt * 32,
                  lds + 16384 + c * 16384 + wid * 4096 + j * 1024);
  };
  auto ldA = [&](int c, int mi) -> bf16x8 {
    int row = mi * 16 + lrow;
    return *(const bf16x8*)(lds + c * 8192 + row * 64 + ((g8 ^ SW(row)) << 4));
  };
  auto ldB = [&](int c, int ni) -> bf16x8 {
    int row = wid * 64 + ni * 16 + lrow;
    return *(const bf16x8*)(lds + 16384 + c * 16384 + row * 64 + ((g8 ^ SW(row)) << 4));
  };

  STAGE(0, 0);

  for (int kt = 0; kt < NKT2; ++kt){
    const int c = kt & 1;
    asm volatile("s_waitcnt vmcnt(0)" ::: "memory");
    __builtin_amdgcn_s_barrier();
    if (kt + 1 < NKT2) STAGE(c ^ 1, kt + 1);

    bf16x8 af[8], bfv[4];
    #pragma unroll
    for (int mi = 0; mi < 8; ++mi) af[mi] = ldA(c, mi);
    #pragma unroll
    for (int ni = 0; ni < 4; ++ni) bfv[ni] = ldB(c, ni);
    #pragma unroll
    for (int mi = 0; mi < 8; ++mi)
      #pragma unroll
      for (int ni = 0; ni < 4; ++ni)
        acc[mi][ni] = __builtin_amdgcn_mfma_f32_16x16x32_bf16(
            af[mi], bfv[ni], acc[mi][ni], 0, 0, 0);
  }

  const int tsel = by >> 3;                 // 0=q, 1=k, 2=v (block-uniform)
  const int hcol = wid >> 1;                // which of the 2 heads in tile
  const int hh = (by & 7) * 2 + hcol;
  if (tsel < 2){
    // ---- fused centered-RMS + rope (pair-permuted, shfl rope) ----
    const float* gv = tsel ? gk : gq;
    const float* bv = tsel ? bk : bq;
    float* red = (float*)lds;               // [128 rows][2 heads][2 half][2]
    float gcoef[4], bcoef[4];
    #pragma unroll
    for (int ni = 0; ni < 4; ++ni){
      int p = (wid & 1) * 64 + ni * 16 + lrow;
      int d = (p >> 1) + ((p & 1) << 6);
      gcoef[ni] = 1.0f + gv[hh * 128 + d];
      bcoef[ni] = bv[hh * 128 + d];
    }
    __syncthreads();
    #pragma unroll
    for (int mi = 0; mi < 8; ++mi)
      #pragma unroll
      for (int r = 0; r < 4; ++r){
        float a0 = acc[mi][0][r], a1 = acc[mi][1][r];
        float a2 = acc[mi][2][r], a3 = acc[mi][3][r];
        float s1 = (a0 + a1) + (a2 + a3);
        float s2 = (a0*a0 + a1*a1) + (a2*a2 + a3*a3);
        #pragma unroll
        for (int off = 1; off < 16; off <<= 1){
          s1 += __shfl_xor(s1, off);
          s2 += __shfl_xor(s2, off);
        }
        if (lrow == 0){
          int row = mi * 16 + g8 * 4 + r;
          red[row * 8 + hcol * 4 + (wid & 1) * 2]     = s1;
          red[row * 8 + hcol * 4 + (wid & 1) * 2 + 1] = s2;
        }
      }
    __syncthreads();
    const float qsc = tsel ? 1.0f : 0.011271055007f;   // log2(e)/128 on q
    const float sgn = (lrow & 1) ? 1.0f : -1.0f;
    short* dstn = Cn + (size_t)tsel * (NB * NH * NT * ND);
    #pragma unroll
    for (int mi = 0; mi < 8; ++mi)
      #pragma unroll
      for (int r = 0; r < 4; ++r){
        int row = mi * 16 + g8 * 4 + r;
        float s1 = red[row * 8 + hcol * 4]     + red[row * 8 + hcol * 4 + 2];
        float s2 = red[row * 8 + hcol * 4 + 1] + red[row * 8 + hcol * 4 + 3];
        float mean = s1 * (1.0f / 128.0f);
        float var = s2 * (1.0f / 128.0f) - mean * mean;
        float rstd = rsqrtf(var + 1e-6f);
        int rowb = m0 + row;
        int b = rowb >> 11, t = rowb & 2047;
        size_t rbase = (((size_t)(b * NH + hh)) * NT + t) * ND;
        #pragma unroll
        for (int ni = 0; ni < 4; ++ni){
          float nv = (acc[mi][ni][r] - mean) * rstd * gcoef[ni] + bcoef[ni];
          float pv = __shfl_xor(nv, 1);     // rope partner (p^1)
          int p = (wid & 1) * 64 + ni * 16 + lrow;
          float c = ctab[t * 64 + (p >> 1)], sn = stab[t * 64 + (p >> 1)];
          float o = (nv * c + sgn * pv * sn) * qsc;
          dstn[rbase + p] = (short)f2bf(o);
        }
      }
  } else {
    // ---- V: tile-transposed bf16x4 stores (standard d layout) ----
    #pragma unroll
    for (int mi = 0; mi < 8; ++mi){
      int rowb = m0 + mi * 16 + g8 * 4;
      int b = rowb >> 11, t0 = rowb & 2047;
      int jb = t0 >> 6, toff = t0 & 63;
      #pragma unroll
      for (int ni = 0; ni < 4; ++ni){
        int d = (wid & 1) * 64 + ni * 16 + lrow;
        f32x4 a = acc[mi][ni];
        bf16x4 w4;
        #pragma unroll
        for (int r = 0; r < 4; ++r) w4[r] = (short)f2bf(a[r]);
        *(bf16x4*)&Cv[(((size_t)(b * NH + hh) * 32 + jb) * ND + d) * 64 + toff] = w4;
      }
    }
  }
}

// ---------------- out-proj GEMM v5: 128x256, BK=32, fp32 out ---------------
__global__ __launch_bounds__(256, 2) void gemmo_k(const short* __restrict__ A,
                                                  const short* __restrict__ Bt,
                                                  float* __restrict__ Cout){
  extern __shared__ char lds[];   // A[2][8KB] @0 | B[2][16KB] @16384
  const int tid = threadIdx.x;
  const int wid = tid >> 6, lane = tid & 63;
  const int lrow = lane & 15, g8 = lane >> 4;
  const int Kdim = 2048;

  // bijective XCD swizzle over 256 blocks
  int bid = blockIdx.x;
  int s = (bid & 7) * 32 + (bid >> 3);
  const int bx = s & 31;        // 32 m-tiles
  const int by = s >> 5;        // 8 n-tiles
  const int m0 = bx * 128, n0 = by * 256;

  const int ar = lane >> 2;
  const int ag = (lane & 3) ^ SW(ar);
  const short* Ab = A  + (size_t)(m0 + wid * 32 + ar) * Kdim + ag * 8;
  const short* Bb = Bt + (size_t)(n0 + wid * 64 + ar) * Kdim + ag * 8;

  f32x4 acc[8][4] = {};

  auto STAGE = [&](int c, int kt){
    #pragma unroll
    for (int i = 0; i < 2; ++i)
      gload_lds16(Ab + (size_t)(i * 16) * Kdim + kt * 32,
                  lds + c * 8192 + wid * 2048 + i * 1024);
    #pragma unroll
    for (int j = 0; j < 4; ++j)
      gload_lds16(Bb + (size_t)(j * 16) * Kdim + kt * 32,
                  lds + 16384 + c * 16384 + wid * 4096 + j * 1024);
  };
  auto ldA = [&](int c, int mi) -> bf16x8 {
    int row = mi * 16 + lrow;
    return *(const bf16x8*)(lds + c * 8192 + row * 64 + ((g8 ^ SW(row)) << 4));
  };
  auto ldB = [&](int c, int ni) -> bf16x8 {
    int row = wid * 64 + ni * 16 + lrow;
    return *(const bf16x8*)(lds + 16384 + c * 16384 + row * 64 + ((g8 ^ SW(row)) << 4));
  };

  STAGE(0, 0);

  for (int kt = 0; kt < NKT2; ++kt){
    const int c = kt & 1;
    asm volatile("s_waitcnt vmcnt(0)" ::: "memory");
    __builtin_amdgcn_s_barrier();
    if (kt + 1 < NKT2) STAGE(c ^ 1, kt + 1);

    bf16x8 af[8], bfv[4];
    #pragma unroll
    for (int mi = 0; mi < 8; ++mi) af[mi] = ldA(c, mi);
    #pragma unroll
    for (int ni = 0; ni < 4; ++ni) bfv[ni] = ldB(c, ni);
    #pragma unroll
    for (int mi = 0; mi < 8; ++mi)
      #pragma unroll
      for (int ni = 0; ni < 4; ++ni)
        acc[mi][ni] = __builtin_amdgcn_mfma_f32_16x16x32_bf16(
            af[mi], bfv[ni], acc[mi][ni], 0, 0, 0);
  }

  #pragma unroll
  for (int mi = 0; mi < 8; ++mi){
    int rowb = m0 + mi * 16 + g8 * 4;
    #pragma unroll
    for (int ni = 0; ni < 4; ++ni){
      int col = n0 + wid * 64 + ni * 16 + lrow;
      f32x4 a = acc[mi][ni];
      #pragma unroll
      for (int r = 0; r < 4; ++r)
        Cout[(size_t)(rowb + r) * 2048 + col] = a[r];
    }
  }
}

// ---------------- flash attention v3: QBLK=128, 8 waves, triple-buffer -----
__global__ __launch_bounds__(512) void attn_k(const short* __restrict__ qn,
                                              const short* __restrict__ kn,
                                              const short* __restrict__ vt,
                                              short* __restrict__ ob){
  extern __shared__ char lds[];
  const int tid = threadIdx.x;
  const int wid = tid >> 6, lane = tid & 63;   // wid 0..7
  const int lrow = lane & 15, g8 = lane >> 4;
  const int id = blockIdx.x;
  const int qs = id >> 5;             // 0..7
  const int bh = id & 31;             // same-bh ids congruent mod 8 -> same XCD
  const int b = bh >> 4, h = bh & 15;
  const size_t base = (size_t)bh * NT * ND;
  char* Pw = lds + 98304 + wid * 2048;

  auto STAGE = [&](int jb){
    const int cb = jb % 3;
    #pragma unroll
    for (int i = 0; i < 2; ++i){
      int r0 = wid * 4 + i * 32;
      int r = r0 + (lane >> 4);
      int g = lane & 15;
      gload_lds16(kn + base + (size_t)(jb * 64 + r) * ND + ((g ^ (r & 7)) << 3),
                  lds + cb * 16384 + r0 * 256);
    }
    #pragma unroll
    for (int i = 0; i < 2; ++i){
      int d0 = wid * 8 + i * 64;
      int d = d0 + (lane >> 3);
      int g = lane & 7;
      gload_lds16(vt + base + (size_t)jb * 8192 + d * 64 + ((g ^ (d & 7)) << 3),
                  lds + 49152 + cb * 16384 + d0 * 128);
    }
  };

  for (int pass = 0; pass < 2; ++pass){
    const int qt = pass ? (15 - qs) : qs;      // supertile of 128 q-rows
    const int t0 = qt * 128;
    const int wrow0 = t0 + wid * 16;
    const int tq = wrow0 + lrow;
    bf16x8 qf[4];
    #pragma unroll
    for (int dc = 0; dc < 4; ++dc)
      qf[dc] = *(const bf16x8*)(qn + base + (size_t)tq * ND + dc * 32 + g8 * 8);
    f32x4 O[8] = {};
    float m = -3e38f, lsum = 0.0f;
    const int ntiles = 2 * qt + 2;

    __syncthreads();             // all reads of LDS from previous pass done
    STAGE(0);
    STAGE(1);

    for (int jb = 0; jb < ntiles; ++jb){
      if (jb + 1 < ntiles) asm volatile("s_waitcnt vmcnt(4)" ::: "memory");
      else                 asm volatile("s_waitcnt vmcnt(0)" ::: "memory");
      __builtin_amdgcn_s_barrier();          // tile jb resident
      if (jb + 2 < ntiles) STAGE(jb + 2);    // write buf (jb+2)%3: readers done
      const char* Kb = lds + (jb % 3) * 16384;
      const char* Vb = lds + 49152 + (jb % 3) * 16384;

      if (jb * 64 <= wrow0 + 15){
        f32x4 st[4] = {};
        __builtin_amdgcn_s_setprio(1);
        #pragma unroll
        for (int dc = 0; dc < 4; ++dc)
          #pragma unroll
          for (int js = 0; js < 4; ++js){
            int jl = js * 16 + lrow;
            bf16x8 kf = *(const bf16x8*)(Kb + jl * 256 +
                          (((dc * 4 + g8) ^ (jl & 7)) << 4));
            st[js] = __builtin_amdgcn_mfma_f32_16x16x32_bf16(kf, qf[dc], st[js], 0, 0, 0);
          }
        __builtin_amdgcn_s_setprio(0);
        if (jb * 64 + 63 > wrow0){
          #pragma unroll
          for (int js = 0; js < 4; ++js)
            #pragma unroll
            for (int r = 0; r < 4; ++r){
              int j = jb * 64 + js * 16 + g8 * 4 + r;
              if (j > tq) st[js][r] = -3e38f;
            }
        }
        f32x4 m4 = st[0];
        #pragma unroll
        for (int js = 1; js < 4; ++js)
          #pragma unroll
          for (int r = 0; r < 4; ++r) m4[r] = fmaxf(m4[r], st[js][r]);
        float mx = fmaxf(fmaxf(m4[0], m4[1]), fmaxf(m4[2], m4[3]));
        mx = fmaxf(mx, __shfl_xor(mx, 16));
        mx = fmaxf(mx, __shfl_xor(mx, 32));
        if (!__all(mx <= m + 8.0f)){
          float mnew = fmaxf(m, mx);
          float fac = exp2f(m - mnew);
          m = mnew;
          lsum *= fac;
          #pragma unroll
          for (int dcb = 0; dcb < 8; ++dcb) O[dcb] *= fac;
        }
        float ps = 0.0f;
        #pragma unroll
        for (int js = 0; js < 4; ++js){
          float p0 = exp2f(st[js][0] - m);
          float p1 = exp2f(st[js][1] - m);
          float p2 = exp2f(st[js][2] - m);
          float p3 = exp2f(st[js][3] - m);
          ps += (p0 + p1) + (p2 + p3);
          unsigned int lo, hi;
          asm("v_cvt_pk_bf16_f32 %0, %1, %2" : "=v"(lo) : "v"(p0), "v"(p1));
          asm("v_cvt_pk_bf16_f32 %0, %1, %2" : "=v"(hi) : "v"(p2), "v"(p3));
          uint2 w; w.x = lo; w.y = hi;
          *(uint2*)(Pw + lrow * 128 + ((js * 32 + g8 * 8) ^ ((lrow & 7) << 4))) = w;
        }
        ps += __shfl_xor(ps, 16);
        ps += __shfl_xor(ps, 32);
        lsum += ps;
        asm volatile("s_waitcnt lgkmcnt(0)" ::: "memory");
        __builtin_amdgcn_s_setprio(1);
        #pragma unroll
        for (int j32 = 0; j32 < 2; ++j32){
          bf16x8 pf = *(const bf16x8*)(Pw + lrow * 128 +
                        ((j32 * 64 + g8 * 16) ^ ((lrow & 7) << 4)));
          #pragma unroll
          for (int dcb = 0; dcb < 8; ++dcb){
            int d = dcb * 16 + lrow;
            bf16x8 vf = *(const bf16x8*)(Vb + d * 128 +
                          (((j32 * 4 + g8) ^ (d & 7)) << 4));
            O[dcb] = __builtin_amdgcn_mfma_f32_16x16x32_bf16(vf, pf, O[dcb], 0, 0, 0);
          }
        }
        __builtin_amdgcn_s_setprio(0);
      }
    }
    float inv = 1.0f / lsum;
    #pragma unroll
    for (int dcb = 0; dcb < 8; ++dcb){
      bf16x4 w4;
      #pragma unroll
      for (int r = 0; r < 4; ++r) w4[r] = (short)f2bf(O[dcb][r] * inv);
      *(bf16x4*)(ob + ((size_t)(b * NT + tq)) * (NH * ND) + h * ND + dcb * 16 + g8 * 4) = w4;
    }
  }
}

// ---------------------------------------------------------------------------
extern "C" void kernel_launch(void* const* d_in, const int* in_sizes, int n_in,
                              void* d_out, int out_size, void* d_ws, size_t ws_size,
                              hipStream_t stream){
  const float* x  = (const float*)d_in[0];
  const float* wq = (const float*)d_in[1];
  const float* wk = (const float*)d_in[2];
  const float* wv = (const float*)d_in[3];
  const float* wo = (const float*)d_in[4];
  const float* gq = (const float*)d_in[5];
  const float* bq = (const float*)d_in[6];
  const float* gk = (const float*)d_in[7];
  const float* bk = (const float*)d_in[8];

  char* ws = (char*)d_ws;
  short* xb   = (short*)(ws);                      // 16,777,216 B
  short* wT   = (short*)(ws + 16777216);           // 33,554,432 B (q,k,v,o ^T)
  short* qkvb = (short*)(ws + 50331648);           // 50,331,648 B (v^T region used)
  short* qkn  = (short*)(ws + 100663296);          // 33,554,432 B (qn|kn)
  short* ob   = (short*)(ws + 134217728);          // 16,777,216 B
  float* ctab = (float*)(ws + 150994944);          // 524,288 B
  float* stab = (float*)(ws + 151519232);          // 524,288 B

  (void)hipFuncSetAttribute((const void*)gemm256_k,
                            hipFuncAttributeMaxDynamicSharedMemorySize, 49152);
  (void)hipFuncSetAttribute((const void*)gemmo_k,
                            hipFuncAttributeMaxDynamicSharedMemorySize, 49152);
  (void)hipFuncSetAttribute((const void*)attn_k,
                            hipFuncAttributeMaxDynamicSharedMemorySize, 114688);

  prep_k<<<dim3(25088), dim3(256), 0, stream>>>(x, wq, wk, wv, wo, xb, wT, ctab, stab);
  gemm256_k<<<dim3(768), dim3(256), 49152, stream>>>(xb, wT,
                                                     qkvb + 2 * (size_t)8388608, qkn,
                                                     gq, bq, gk, bk, ctab, stab);
  attn_k<<<dim3(256), dim3(512), 114688, stream>>>(qkn, qkn + 8388608,
                                                   qkvb + 2 * (size_t)8388608, ob);
  gemmo_k<<<dim3(256), dim3(256), 49152, stream>>>(ob, wT + 3 * (size_t)4194304,
                                                   (float*)d_out);
}

// Round 18
// 256.775 us; speedup vs baseline: 1.1120x; 1.1120x over previous
//
#include <hip/hip_runtime.h>

// ---------------------------------------------------------------------------
// Fused MHA: B=2, T=2048, M=2048, H=16, D=128, causal, qk-centered-RMS-norm,
// half-split rotary, QK_SCALE = 1/D.
// Pipeline: prep (cast|transpose|rope fused) -> QKV GEMM v3 (256x128, BK=32,
// waves tile M only: 32 rows x 128 cols each -> register-only fused
// norm+rope epilogue) -> flash attn v3 -> out GEMM v2 (fp32 out).
// (R15 configuration — best measured: 256.9 us)
// ---------------------------------------------------------------------------

#define NB 2
#define NT 2048
#define NM 2048
#define NH 16
#define ND 128

typedef __attribute__((ext_vector_type(4))) float f32x4;
typedef __attribute__((ext_vector_type(8))) short bf16x8;
typedef __attribute__((ext_vector_type(4))) short bf16x4;

#define AS1 __attribute__((address_space(1)))
#define AS3 __attribute__((address_space(3)))

#define SW(r) (((r) ^ ((r) >> 2)) & 3)

__device__ __forceinline__ unsigned short f2bf(float f){
  unsigned int u = __float_as_uint(f);
  u = (u + 0x7fffu + ((u >> 16) & 1u)) >> 16;   // RNE
  return (unsigned short)u;
}
__device__ __forceinline__ float bf2f(short s){
  return __uint_as_float(((unsigned int)(unsigned short)s) << 16);
}
__device__ __forceinline__ void gload_lds16(const void* g, void* l){
  __builtin_amdgcn_global_load_lds((const AS1 void*)g, (AS3 void*)l, 16, 0, 0);
}

// ------------- fused prep: cast x | transpose weights | rope table ---------
__global__ __launch_bounds__(256) void prep_k(const float* __restrict__ x,
                                              const float* __restrict__ wq,
                                              const float* __restrict__ wk,
                                              const float* __restrict__ wv,
                                              const float* __restrict__ wo,
                                              short* __restrict__ xb,
                                              short* __restrict__ wT,
                                              float* __restrict__ ctab,
                                              float* __restrict__ stab){
  __shared__ float tl[32][33];
  const int bid = blockIdx.x, tid = threadIdx.x;
  if (bid < 8192){
    size_t gid = (size_t)bid * 256 + tid;
    float4 v = *(const float4*)(x + gid * 4);
    bf16x4 o;
    o[0] = (short)f2bf(v.x); o[1] = (short)f2bf(v.y);
    o[2] = (short)f2bf(v.z); o[3] = (short)f2bf(v.w);
    *(bf16x4*)(xb + gid * 4) = o;
  } else if (bid < 24576){
    int tb = bid - 8192;
    int z = tb >> 12, rem = tb & 4095;
    int n0 = (rem & 63) * 32, k0 = (rem >> 6) * 32;
    const float* src = (z == 0) ? wq : (z == 1) ? wk : (z == 2) ? wv : wo;
    short* dst = wT + (size_t)z * 2048 * 2048;
    int cx = tid & 31, ry = tid >> 5; // 0..7
    #pragma unroll
    for (int p = 0; p < 4; ++p)
      tl[ry + 8 * p][cx] = src[(size_t)(k0 + ry + 8 * p) * 2048 + n0 + cx];
    __syncthreads();
    #pragma unroll
    for (int p = 0; p < 4; ++p)
      dst[(size_t)(n0 + ry + 8 * p) * 2048 + k0 + cx] =
          (short)f2bf(tl[cx][ry + 8 * p]);
  } else {
    int t = (bid - 24576) * 4 + (tid >> 6);
    int i = tid & 63;
    float freq = __expf(-(float)i * (9.210340371976184f / 64.0f)); // ln(10000)
    float ang = (float)t * freq;
    ctab[t * 64 + i] = cosf(ang);
    stab[t * 64 + i] = sinf(ang);
  }
}

// ---------------------------------------------------------------------------
// QKV GEMM v3: 256x128 tile, BK=32, 8 waves x (32 rows x 128 cols), 512 thr,
// 48 KiB LDS, 2 blocks/CU. Each lane holds full d-range of its rows ->
// register-only centered-RMS + rope + log2e/128 epilogue (no LDS, no syncs).
// V written tile-transposed.
// ---------------------------------------------------------------------------
#define NKT2 64   // 2048 / 32
__global__ __launch_bounds__(512, 4) void gemm256_k(const short* __restrict__ A,
                                                    const short* __restrict__ Bt,
                                                    short* __restrict__ Cv,
                                                    short* __restrict__ Cn,
                                                    const float* __restrict__ gq,
                                                    const float* __restrict__ bq,
                                                    const float* __restrict__ gk,
                                                    const float* __restrict__ bk,
                                                    const float* __restrict__ ctab,
                                                    const float* __restrict__ stab){
  extern __shared__ char lds[];   // A[2][16KB] @0 | B[2][8KB] @32768
  const int tid = threadIdx.x;
  const int wid = tid >> 6, lane = tid & 63;
  const int lrow = lane & 15, g8 = lane >> 4;
  const int Kdim = 2048;

  // XCD-aware bijective swizzle over 768 blocks (768 % 8 == 0)
  int bid = blockIdx.x;
  int s = (bid & 7) * 96 + (bid >> 3);
  const int bx = s & 15;        // 16 m-tiles (256 rows)
  const int by = s >> 4;        // 48 n-tiles (128 cols)
  const int m0 = bx * 256, n0 = by * 128;

  const int ar = lane >> 2;
  const int ag = (lane & 3) ^ SW(ar);
  const short* Ab = A  + (size_t)(m0 + wid * 32 + ar) * Kdim + ag * 8;
  const short* Bb = Bt + (size_t)(n0 + wid * 16 + ar) * Kdim + ag * 8;

  f32x4 acc[2][8] = {};

  auto STAGE = [&](int c, int kt){
    #pragma unroll
    for (int i = 0; i < 2; ++i)
      gload_lds16(Ab + (size_t)(i * 16) * Kdim + kt * 32,
                  lds + c * 16384 + wid * 2048 + i * 1024);
    gload_lds16(Bb + kt * 32, lds + 32768 + c * 8192 + wid * 1024);
  };
  auto ldA = [&](int c, int mi) -> bf16x8 {
    int row = wid * 32 + mi * 16 + lrow;
    return *(const bf16x8*)(lds + c * 16384 + row * 64 + ((g8 ^ SW(row)) << 4));
  };
  auto ldB = [&](int c, int ni) -> bf16x8 {
    int row = ni * 16 + lrow;
    return *(const bf16x8*)(lds + 32768 + c * 8192 + row * 64 + ((g8 ^ SW(row)) << 4));
  };

  STAGE(0, 0);

  for (int kt = 0; kt < NKT2; ++kt){
    const int c = kt & 1;
    asm volatile("s_waitcnt vmcnt(0)" ::: "memory");
    __builtin_amdgcn_s_barrier();
    if (kt + 1 < NKT2) STAGE(c ^ 1, kt + 1);

    bf16x8 af[2], bfv[8];
    #pragma unroll
    for (int mi = 0; mi < 2; ++mi) af[mi] = ldA(c, mi);
    #pragma unroll
    for (int ni = 0; ni < 8; ++ni) bfv[ni] = ldB(c, ni);
    #pragma unroll
    for (int mi = 0; mi < 2; ++mi)
      #pragma unroll
      for (int ni = 0; ni < 8; ++ni)
        acc[mi][ni] = __builtin_amdgcn_mfma_f32_16x16x32_bf16(
            af[mi], bfv[ni], acc[mi][ni], 0, 0, 0);
  }

  const int tsel = by >> 4;           // 0=q, 1=k, 2=v (block-uniform)
  const int hh = by & 15;             // single head per tile
  if (tsel < 2){
    // ---- register-only fused centered-RMS + rope epilogue ----
    const float* gv = tsel ? gk : gq;
    const float* bv = tsel ? bk : bq;
    float gcoef[8], bcoef[8];
    #pragma unroll
    for (int ni = 0; ni < 8; ++ni){
      int d = ni * 16 + lrow;
      gcoef[ni] = 1.0f + gv[hh * 128 + d];
      bcoef[ni] = bv[hh * 128 + d];
    }
    const float qsc = tsel ? 1.0f : 0.011271055007f;   // log2(e)/128 on q
    short* dstn = Cn + (size_t)tsel * (NB * NH * NT * ND);
    #pragma unroll
    for (int mi = 0; mi < 2; ++mi)
      #pragma unroll
      for (int r = 0; r < 4; ++r){
        float s1 = 0.0f, s2 = 0.0f;
        #pragma unroll
        for (int ni = 0; ni < 8; ++ni){
          float v = acc[mi][ni][r];
          s1 += v; s2 += v * v;
        }
        #pragma unroll
        for (int off = 1; off < 16; off <<= 1){
          s1 += __shfl_xor(s1, off);
          s2 += __shfl_xor(s2, off);
        }
        float mean = s1 * (1.0f / 128.0f);
        float var = s2 * (1.0f / 128.0f) - mean * mean;
        float rstd = rsqrtf(var + 1e-6f);
        float nv[8];
        #pragma unroll
        for (int ni = 0; ni < 8; ++ni)
          nv[ni] = (acc[mi][ni][r] - mean) * rstd * gcoef[ni] + bcoef[ni];
        int rowb = m0 + wid * 32 + mi * 16 + g8 * 4 + r;
        int b = rowb >> 11, t = rowb & 2047;
        size_t rbase = (((size_t)(b * NH + hh)) * NT + t) * ND;
        #pragma unroll
        for (int lo = 0; lo < 4; ++lo){
          int dl = lo * 16 + lrow;
          float c = ctab[t * 64 + dl], sn = stab[t * 64 + dl];
          float oe = (nv[lo] * c - nv[lo + 4] * sn) * qsc;
          float oo = (nv[lo] * sn + nv[lo + 4] * c) * qsc;
          dstn[rbase + dl]      = (short)f2bf(oe);
          dstn[rbase + dl + 64] = (short)f2bf(oo);
        }
      }
  } else {
    // ---- V: tile-transposed bf16x4 stores ----
    #pragma unroll
    for (int mi = 0; mi < 2; ++mi){
      int rowb = m0 + wid * 32 + mi * 16 + g8 * 4;
      int b = rowb >> 11, t0 = rowb & 2047;
      int jb = t0 >> 6, toff = t0 & 63;
      #pragma unroll
      for (int ni = 0; ni < 8; ++ni){
        int d = ni * 16 + lrow;
        f32x4 a = acc[mi][ni];
        bf16x4 w4;
        #pragma unroll
        for (int r = 0; r < 4; ++r) w4[r] = (short)f2bf(a[r]);
        *(bf16x4*)&Cv[(((size_t)(b * NH + hh) * 32 + jb) * ND + d) * 64 + toff] = w4;
      }
    }
  }
}

// ---------------- out-proj GEMM v2: 256x128, BK=32, fp32 out ---------------
__global__ __launch_bounds__(512, 4) void gemmo_k(const short* __restrict__ A,
                                                  const short* __restrict__ Bt,
                                                  float* __restrict__ Cout){
  extern __shared__ char lds[];
  const int tid = threadIdx.x;
  const int wid = tid >> 6, lane = tid & 63;
  const int lrow = lane & 15, g8 = lane >> 4;
  const int wm = wid >> 1, wn = wid & 1;
  const int Kdim = 2048;

  int bid = blockIdx.x;
  int s = (bid & 7) * 32 + (bid >> 3);
  const int bx = s & 15;
  const int by = s >> 4;
  const int m0 = bx * 256, n0 = by * 128;

  const int ar = lane >> 2;
  const int ag = (lane & 3) ^ SW(ar);
  const short* Ab = A  + (size_t)(m0 + wid * 32 + ar) * Kdim + ag * 8;
  const short* Bb = Bt + (size_t)(n0 + wid * 16 + ar) * Kdim + ag * 8;

  f32x4 acc[4][4] = {};

  auto STAGE = [&](int c, int kt){
    #pragma unroll
    for (int i = 0; i < 2; ++i)
      gload_lds16(Ab + (size_t)(i * 16) * Kdim + kt * 32,
                  lds + c * 16384 + wid * 2048 + i * 1024);
    gload_lds16(Bb + kt * 32, lds + 32768 + c * 8192 + wid * 1024);
  };
  auto ldA = [&](int c, int mi) -> bf16x8 {
    int row = wm * 64 + mi * 16 + lrow;
    return *(const bf16x8*)(lds + c * 16384 + row * 64 + ((g8 ^ SW(row)) << 4));
  };
  auto ldB = [&](int c, int ni) -> bf16x8 {
    int row = wn * 64 + ni * 16 + lrow;
    return *(const bf16x8*)(lds + 32768 + c * 8192 + row * 64 + ((g8 ^ SW(row)) << 4));
  };

  STAGE(0, 0);

  for (int kt = 0; kt < NKT2; ++kt){
    const int c = kt & 1;
    asm volatile("s_waitcnt vmcnt(0)" ::: "memory");
    __builtin_amdgcn_s_barrier();
    if (kt + 1 < NKT2) STAGE(c ^ 1, kt + 1);

    bf16x8 af[4], bfv[4];
    #pragma unroll
    for (int mi = 0; mi < 4; ++mi) af[mi] = ldA(c, mi);
    #pragma unroll
    for (int ni = 0; ni < 4; ++ni) bfv[ni] = ldB(c, ni);
    #pragma unroll
    for (int mi = 0; mi < 4; ++mi)
      #pragma unroll
      for (int ni = 0; ni < 4; ++ni)
        acc[mi][ni] = __builtin_amdgcn_mfma_f32_16x16x32_bf16(
            af[mi], bfv[ni], acc[mi][ni], 0, 0, 0);
  }

  #pragma unroll
  for (int mi = 0; mi < 4; ++mi){
    int rowb = m0 + wm * 64 + mi * 16 + g8 * 4;
    #pragma unroll
    for (int ni = 0; ni < 4; ++ni){
      int col = n0 + wn * 64 + ni * 16 + lrow;
      f32x4 a = acc[mi][ni];
      #pragma unroll
      for (int r = 0; r < 4; ++r)
        Cout[(size_t)(rowb + r) * 2048 + col] = a[r];
    }
  }
}

// ---------------- flash attention v3: QBLK=128, 8 waves, triple-buffer -----
__global__ __launch_bounds__(512) void attn_k(const short* __restrict__ qn,
                                              const short* __restrict__ kn,
                                              const short* __restrict__ vt,
                                              short* __restrict__ ob){
  extern __shared__ char lds[];
  const int tid = threadIdx.x;
  const int wid = tid >> 6, lane = tid & 63;   // wid 0..7
  const int lrow = lane & 15, g8 = lane >> 4;
  const int id = blockIdx.x;
  const int qs = id >> 5;             // 0..7
  const int bh = id & 31;             // same-bh ids congruent mod 8 -> same XCD
  const int b = bh >> 4, h = bh & 15;
  const size_t base = (size_t)bh * NT * ND;
  char* Pw = lds + 98304 + wid * 2048;

  auto STAGE = [&](int jb){
    const int cb = jb % 3;
    #pragma unroll
    for (int i = 0; i < 2; ++i){
      int r0 = wid * 4 + i * 32;
      int r = r0 + (lane >> 4);
      int g = lane & 15;
      gload_lds16(kn + base + (size_t)(jb * 64 + r) * ND + ((g ^ (r & 7)) << 3),
                  lds + cb * 16384 + r0 * 256);
    }
    #pragma unroll
    for (int i = 0; i < 2; ++i){
      int d0 = wid * 8 + i * 64;
      int d = d0 + (lane >> 3);
      int g = lane & 7;
      gload_lds16(vt + base + (size_t)jb * 8192 + d * 64 + ((g ^ (d & 7)) << 3),
                  lds + 49152 + cb * 16384 + d0 * 128);
    }
  };

  for (int pass = 0; pass < 2; ++pass){
    const int qt = pass ? (15 - qs) : qs;      // supertile of 128 q-rows
    const int t0 = qt * 128;
    const int wrow0 = t0 + wid * 16;
    const int tq = wrow0 + lrow;
    bf16x8 qf[4];
    #pragma unroll
    for (int dc = 0; dc < 4; ++dc)
      qf[dc] = *(const bf16x8*)(qn + base + (size_t)tq * ND + dc * 32 + g8 * 8);
    f32x4 O[8] = {};
    float m = -3e38f, lsum = 0.0f;
    const int ntiles = 2 * qt + 2;

    __syncthreads();             // all reads of LDS from previous pass done
    STAGE(0);
    STAGE(1);

    for (int jb = 0; jb < ntiles; ++jb){
      if (jb + 1 < ntiles) asm volatile("s_waitcnt vmcnt(4)" ::: "memory");
      else                 asm volatile("s_waitcnt vmcnt(0)" ::: "memory");
      __builtin_amdgcn_s_barrier();          // tile jb resident
      if (jb + 2 < ntiles) STAGE(jb + 2);    // write buf (jb+2)%3: readers done
      const char* Kb = lds + (jb % 3) * 16384;
      const char* Vb = lds + 49152 + (jb % 3) * 16384;

      if (jb * 64 <= wrow0 + 15){
        f32x4 st[4] = {};
        __builtin_amdgcn_s_setprio(1);
        #pragma unroll
        for (int dc = 0; dc < 4; ++dc)
          #pragma unroll
          for (int js = 0; js < 4; ++js){
            int jl = js * 16 + lrow;
            bf16x8 kf = *(const bf16x8*)(Kb + jl * 256 +
                          (((dc * 4 + g8) ^ (jl & 7)) << 4));
            st[js] = __builtin_amdgcn_mfma_f32_16x16x32_bf16(kf, qf[dc], st[js], 0, 0, 0);
          }
        __builtin_amdgcn_s_setprio(0);
        if (jb * 64 + 63 > wrow0){
          #pragma unroll
          for (int js = 0; js < 4; ++js)
            #pragma unroll
            for (int r = 0; r < 4; ++r){
              int j = jb * 64 + js * 16 + g8 * 4 + r;
              if (j > tq) st[js][r] = -3e38f;
            }
        }
        f32x4 m4 = st[0];
        #pragma unroll
        for (int js = 1; js < 4; ++js)
          #pragma unroll
          for (int r = 0; r < 4; ++r) m4[r] = fmaxf(m4[r], st[js][r]);
        float mx = fmaxf(fmaxf(m4[0], m4[1]), fmaxf(m4[2], m4[3]));
        mx = fmaxf(mx, __shfl_xor(mx, 16));
        mx = fmaxf(mx, __shfl_xor(mx, 32));
        if (!__all(mx <= m + 8.0f)){
          float mnew = fmaxf(m, mx);
          float fac = exp2f(m - mnew);
          m = mnew;
          lsum *= fac;
          #pragma unroll
          for (int dcb = 0; dcb < 8; ++dcb) O[dcb] *= fac;
        }
        float ps = 0.0f;
        #pragma unroll
        for (int js = 0; js < 4; ++js){
          float p0 = exp2f(st[js][0] - m);
          float p1 = exp2f(st[js][1] - m);
          float p2 = exp2f(st[js][2] - m);
          float p3 = exp2f(st[js][3] - m);
          ps += (p0 + p1) + (p2 + p3);
          unsigned int lo, hi;
          asm("v_cvt_pk_bf16_f32 %0, %1, %2" : "=v"(lo) : "v"(p0), "v"(p1));
          asm("v_cvt_pk_bf16_f32 %0, %1, %2" : "=v"(hi) : "v"(p2), "v"(p3));
          uint2 w; w.x = lo; w.y = hi;
          *(uint2*)(Pw + lrow * 128 + ((js * 32 + g8 * 8) ^ ((lrow & 7) << 4))) = w;
        }
        ps += __shfl_xor(ps, 16);
        ps += __shfl_xor(ps, 32);
        lsum += ps;
        asm volatile("s_waitcnt lgkmcnt(0)" ::: "memory");
        __builtin_amdgcn_s_setprio(1);
        #pragma unroll
        for (int j32 = 0; j32 < 2; ++j32){
          bf16x8 pf = *(const bf16x8*)(Pw + lrow * 128 +
                        ((j32 * 64 + g8 * 16) ^ ((lrow & 7) << 4)));
          #pragma unroll
          for (int dcb = 0; dcb < 8; ++dcb){
            int d = dcb * 16 + lrow;
            bf16x8 vf = *(const bf16x8*)(Vb + d * 128 +
                          (((j32 * 4 + g8) ^ (d & 7)) << 4));
            O[dcb] = __builtin_amdgcn_mfma_f32_16x16x32_bf16(vf, pf, O[dcb], 0, 0, 0);
          }
        }
        __builtin_amdgcn_s_setprio(0);
      }
    }
    float inv = 1.0f / lsum;
    #pragma unroll
    for (int dcb = 0; dcb < 8; ++dcb){
      bf16x4 w4;
      #pragma unroll
      for (int r = 0; r < 4; ++r) w4[r] = (short)f2bf(O[dcb][r] * inv);
      *(bf16x4*)(ob + ((size_t)(b * NT + tq)) * (NH * ND) + h * ND + dcb * 16 + g8 * 4) = w4;
    }
  }
}

// ---------------------------------------------------------------------------
extern "C" void kernel_launch(void* const* d_in, const int* in_sizes, int n_in,
                              void* d_out, int out_size, void* d_ws, size_t ws_size,
                              hipStream_t stream){
  const float* x  = (const float*)d_in[0];
  const float* wq = (const float*)d_in[1];
  const float* wk = (const float*)d_in[2];
  const float* wv = (const float*)d_in[3];
  const float* wo = (const float*)d_in[4];
  const float* gq = (const float*)d_in[5];
  const float* bq = (const float*)d_in[6];
  const float* gk = (const float*)d_in[7];
  const float* bk = (const float*)d_in[8];

  char* ws = (char*)d_ws;
  short* xb   = (short*)(ws);                      // 16,777,216 B
  short* wT   = (short*)(ws + 16777216);           // 33,554,432 B (q,k,v,o ^T)
  short* qkvb = (short*)(ws + 50331648);           // 50,331,648 B (v^T region used)
  short* qkn  = (short*)(ws + 100663296);          // 33,554,432 B (qn|kn)
  short* ob   = (short*)(ws + 134217728);          // 16,777,216 B
  float* ctab = (float*)(ws + 150994944);          // 524,288 B
  float* stab = (float*)(ws + 151519232);          // 524,288 B

  (void)hipFuncSetAttribute((const void*)gemm256_k,
                            hipFuncAttributeMaxDynamicSharedMemorySize, 49152);
  (void)hipFuncSetAttribute((const void*)gemmo_k,
                            hipFuncAttributeMaxDynamicSharedMemorySize, 49152);
  (void)hipFuncSetAttribute((const void*)attn_k,
                            hipFuncAttributeMaxDynamicSharedMemorySize, 114688);

  prep_k<<<dim3(25088), dim3(256), 0, stream>>>(x, wq, wk, wv, wo, xb, wT, ctab, stab);
  gemm256_k<<<dim3(768), dim3(512), 49152, stream>>>(xb, wT,
                                                     qkvb + 2 * (size_t)8388608, qkn,
                                                     gq, bq, gk, bk, ctab, stab);
  attn_k<<<dim3(256), dim3(512), 114688, stream>>>(qkn, qkn + 8388608,
                                                   qkvb + 2 * (size_t)8388608, ob);
  gemmo_k<<<dim3(256), dim3(512), 49152, stream>>>(ob, wT + 3 * (size_t)4194304,
                                                   (float*)d_out);
}